// Round 7
// baseline (194.075 us; speedup 1.0000x reference)
//
#include <hip/hip_runtime.h>
#include <math.h>

typedef _Float16 half8 __attribute__((ext_vector_type(8)));
typedef float floatx4 __attribute__((ext_vector_type(4)));
typedef float floatx2 __attribute__((ext_vector_type(2)));

#define B_ 8
#define S_ 4096
// scale = 1/sqrt(128) * log2(e): folded into Q so softmax exp is one v_exp_f32
#define SCALE_L2E 0.12751743008389106f
#define MASK_L2E  -14426.950408889634f   // -10000*log2(e): exp2 -> exact 0
#define L2_10K_OVER_128 0.10381025296522975f  // log2(10000)/128

#define PLD 72    // P LDS row stride (halfs) = 144B, 16B-aligned
#define KW  136   // prep K LDS row stride (halfs)
#define VW  40    // prep V^T LDS row stride (halfs)
#define OSTLD 136 // O-staging LDS row stride (halfs); 16xOSTLD fits in P region
#define SLOTS_PER_B 576   // sum over qt32 of ceil(tiles/8)

// units before q-block qt32 (chunks = (qt32>>4)+1)
__device__ __forceinline__ int chunk_prefix(int qt32) {
    int g = qt32 >> 4;
    return qt32 + 8 * g * (g - 1) + (qt32 - (g << 4)) * g;
}

// ---------------- kernel 1: prep ----------------
// grid (128, 8), block 512: 32 seq rows per block.
//  Qh: RoPE(Q)*SCALE_L2E fp16 row-major [b][s][d]
//  Kp: frag-major: chunk(b,s16,c)[lane=quad*16+n][j] = K[s16*16+n][c*32+quad*8+j]
//  Vp: frag-major: chunk(b,kt,c2,nt)[lane=quad*16+n][j] = V[kt*64+c2*32+quad*8+j][nt*16+n]
__global__ __launch_bounds__(512) void prep_kernel(const float* __restrict__ qkv,
                                                   _Float16* __restrict__ Qh,
                                                   _Float16* __restrict__ Kp,
                                                   _Float16* __restrict__ Vp) {
    __shared__ __align__(16) _Float16 Kl[32][KW];
    __shared__ __align__(16) _Float16 Vt[128][VW];
    const int tid = threadIdx.x;
    const int b   = blockIdx.y;
    const int s0  = blockIdx.x * 32;

    // RoPE Q (to global) + K (to LDS): 32 rows x 64 pairs
#pragma unroll
    for (int it = 0; it < 4; ++it) {
        int idx = tid + it * 512;
        int i = idx & 63, sr = idx >> 6, s = s0 + sr;
        const float* base = qkv + ((size_t)(b * S_ + s)) * 384 + 2 * i;
        floatx2 q2 = *(const floatx2*)base;
        floatx2 k2 = *(const floatx2*)(base + 128);
        float inv = exp2f(-(float)(2 * i) * L2_10K_OVER_128);
        float ang = (float)s * inv;
        float sn, cs;
        __sincosf(ang, &sn, &cs);
        size_t oq = ((size_t)(b * S_ + s)) * 128 + 2 * i;
        Qh[oq]     = (_Float16)((q2[0] * cs - q2[1] * sn) * SCALE_L2E);
        Qh[oq + 1] = (_Float16)((q2[0] * sn + q2[1] * cs) * SCALE_L2E);
        Kl[sr][2 * i]     = (_Float16)(k2[0] * cs - k2[1] * sn);
        Kl[sr][2 * i + 1] = (_Float16)(k2[0] * sn + k2[1] * cs);
    }
    // V -> LDS transpose: 32 rows x 32 float4 chunks
#pragma unroll
    for (int it = 0; it < 2; ++it) {
        int idx = tid + it * 512;
        int c = idx & 31, sr = idx >> 5;
        floatx4 v = *(const floatx4*)(qkv + ((size_t)(b * S_ + s0 + sr)) * 384 + 256 + c * 4);
#pragma unroll
        for (int j = 0; j < 4; ++j) Vt[c * 4 + j][sr] = (_Float16)v[j];
    }
    __syncthreads();

    {   // K frag-major out: 2 s16-tiles x 4 c x 64 lanes = 512 chunks
        int t = tid >> 8, c = (tid >> 6) & 3, lane = tid & 63;
        int quad = lane >> 4, n = lane & 15;
        half8 val = *(const half8*)&Kl[t * 16 + n][c * 32 + quad * 8];
        int s16 = (s0 >> 4) + t;
        *(half8*)(Kp + (((size_t)(b * 256 + s16) * 4 + c) * 64 + lane) * 8) = val;
    }
    {   // V frag-major out: this block covers (kt = s0>>6, c2 = (s0>>5)&1)
        int kt = s0 >> 6, c2 = (s0 >> 5) & 1;
        int nt = tid >> 6, lane = tid & 63;
        int quad = lane >> 4, n = lane & 15;
        half8 val = *(const half8*)&Vt[nt * 16 + n][quad * 8];
        *(half8*)(Vp + ((((size_t)(b * 64 + kt) * 2 + c2) * 8 + nt) * 64 + lane) * 8) = val;
    }
}

// ---------------- kernel 2a: split-K flash, PARTIAL-STORE path ----------------
// grid (16,128), block 256 = 4 INDEPENDENT wave-units (no barriers).
// unit ux = bx*4+wid: b = ux>>3, chunk = ux&7; q-block = 127-blockIdx.y.
// Each wave: <=8 K-tiles, M=32 Q rows, fp16 O-partial + f32 l-partial to
// a private slot (plain streaming stores; no atomics).
__global__ __launch_bounds__(256) void attn_part_kernel(const _Float16* __restrict__ Qh,
                                                        const _Float16* __restrict__ Kp,
                                                        const _Float16* __restrict__ Vp,
                                                        _Float16* __restrict__ Ppart,
                                                        float* __restrict__ Lpart) {
    // per-wave LDS slice: 2 tiles x 16 x PLD halfs (single-buffered: same-wave
    // DS ops are in-order, so P write-after-read across tiles needs no dbuf)
    __shared__ __align__(16) _Float16 SH[4][2 * 16 * PLD];

    const int tid   = threadIdx.x;
    const int wid   = tid >> 6;
    const int lane  = tid & 63;
    const int quad  = lane >> 4;
    const int l16   = lane & 15;
    const int ux    = blockIdx.x * 4 + wid;
    const int b     = ux >> 3;
    const int chunk = ux & 7;
    const int qt32  = 127 - blockIdx.y;     // big q-blocks first
    const int qr0   = qt32 * 32;
    const int kt_max = (qr0 + 31) >> 6;     // = qt32>>1
    const int c0    = chunk * 8;
    if (c0 > kt_max) return;
    const int kend  = min(kt_max, c0 + 7);
    const int slot  = b * SLOTS_PER_B + chunk_prefix(qt32) + chunk;
    _Float16* sh = SH[wid];

    half8 aq[2][4];
#pragma unroll
    for (int tile = 0; tile < 2; ++tile) {
        const _Float16* Qb = Qh + ((size_t)(b * S_) + qr0 + tile * 16 + l16) * 128;
#pragma unroll
        for (int c = 0; c < 4; ++c) aq[tile][c] = *(const half8*)(Qb + c * 32 + quad * 8);
    }

    floatx4 o[2][8];
#pragma unroll
    for (int tile = 0; tile < 2; ++tile)
#pragma unroll
        for (int i = 0; i < 8; ++i) o[tile][i] = (floatx4){0.f, 0.f, 0.f, 0.f};
    float rsum[2][4] = {{0.f, 0.f, 0.f, 0.f}, {0.f, 0.f, 0.f, 0.f}};

    const _Float16* Kb = Kp + (size_t)b * 524288;
    const _Float16* Vb = Vp + (size_t)b * 524288;

    for (int kt = c0; kt <= kend; ++kt) {
        // S = Q K^T : K frags loaded once, shared by both M-tiles
        floatx4 s4[2][4];
#pragma unroll
        for (int t = 0; t < 4; ++t) {
            const _Float16* kp = Kb + (((size_t)(kt * 16 + t * 4)) * 64 + lane) * 8;
            half8 bk[4];
#pragma unroll
            for (int c = 0; c < 4; ++c) bk[c] = *(const half8*)(kp + c * 512);
            floatx4 a0 = (floatx4){0.f, 0.f, 0.f, 0.f};
            floatx4 a1 = (floatx4){0.f, 0.f, 0.f, 0.f};
#pragma unroll
            for (int c = 0; c < 4; ++c) {
                a0 = __builtin_amdgcn_mfma_f32_16x16x32_f16(aq[0][c], bk[c], a0, 0, 0, 0);
                a1 = __builtin_amdgcn_mfma_f32_16x16x32_f16(aq[1][c], bk[c], a1, 0, 0, 0);
            }
            s4[0][t] = a0; s4[1][t] = a1;
        }

        if (kt == kt_max) {  // causal mask, diagonal tile only
#pragma unroll
            for (int tile = 0; tile < 2; ++tile)
#pragma unroll
                for (int t = 0; t < 4; ++t)
#pragma unroll
                    for (int r = 0; r < 4; ++r) {
                        int kcol = kt * 64 + t * 16 + l16;
                        int qr   = qr0 + tile * 16 + quad * 4 + r;
                        if (kcol > qr) s4[tile][t][r] += MASK_L2E;
                    }
        }

        // p = exp2(s), lane-local l, P -> LDS (C->A layout transform)
#pragma unroll
        for (int tile = 0; tile < 2; ++tile)
#pragma unroll
            for (int t = 0; t < 4; ++t)
#pragma unroll
                for (int r = 0; r < 4; ++r) {
                    float p = __builtin_amdgcn_exp2f(s4[tile][t][r]);
                    rsum[tile][r] += p;
                    sh[tile * (16 * PLD) + (quad * 4 + r) * PLD + t * 16 + l16] = (_Float16)p;
                }

        // O += P V : V frags loaded once per c2, shared by both M-tiles
#pragma unroll
        for (int c2 = 0; c2 < 2; ++c2) {
            half8 vf[8];
#pragma unroll
            for (int nt = 0; nt < 8; ++nt)
                vf[nt] = *(const half8*)(Vb + (((size_t)(kt * 2 + c2) * 8 + nt) * 64 + lane) * 8);
#pragma unroll
            for (int tile = 0; tile < 2; ++tile) {
                half8 ap = *(const half8*)&sh[tile * (16 * PLD) + l16 * PLD + c2 * 32 + quad * 8];
#pragma unroll
                for (int nt = 0; nt < 8; ++nt)
                    o[tile][nt] = __builtin_amdgcn_mfma_f32_16x16x32_f16(ap, vf[nt], o[tile][nt], 0, 0, 0);
            }
        }
    }

    // l partials: reduce over l16, plain store
#pragma unroll
    for (int off = 1; off <= 8; off <<= 1)
#pragma unroll
        for (int tile = 0; tile < 2; ++tile)
#pragma unroll
            for (int r = 0; r < 4; ++r)
                rsum[tile][r] += __shfl_xor(rsum[tile][r], off, 64);
    if (l16 == 0) {
#pragma unroll
        for (int tile = 0; tile < 2; ++tile)
#pragma unroll
            for (int r = 0; r < 4; ++r)
                Lpart[(size_t)slot * 32 + tile * 16 + quad * 4 + r] = rsum[tile][r];
    }

    // O partial: per tile, C-layout -> LDS fp16 staging -> coalesced 16B stores
    // (in-order same-wave DS => reuse of the P region is safe)
    _Float16* Ost = sh;   // 16 x OSTLD = 2176 halfs <= 2304 (per-tile staging)
    _Float16* pp = Ppart + (size_t)slot * 4096;
#pragma unroll
    for (int tile = 0; tile < 2; ++tile) {
#pragma unroll
        for (int nt = 0; nt < 8; ++nt)
#pragma unroll
            for (int r = 0; r < 4; ++r)
                Ost[(quad * 4 + r) * OSTLD + nt * 16 + l16] = (_Float16)o[tile][nt][r];
#pragma unroll
        for (int i = 0; i < 4; ++i) {
            int idx = lane + i * 64;        // 16 rows x 16 half8-groups
            half8 v = *(const half8*)&Ost[(idx >> 4) * OSTLD + (idx & 15) * 8];
            *(half8*)(pp + (size_t)(tile * 2048 + idx * 8)) = v;
        }
    }
}

// ---------------- kernel 2b: reduce partials + normalize ----------------
// grid 1024 (= B x 128 q-blocks), block 256. Sums <=8 fp16 partials, divides by l.
__global__ __launch_bounds__(256) void reduce_kernel(const _Float16* __restrict__ Ppart,
                                                     const float* __restrict__ Lpart,
                                                     float* __restrict__ out) {
    const int bid  = blockIdx.x;
    const int b    = bid >> 7;
    const int qt32 = bid & 127;
    const int qr0  = qt32 * 32;
    const int nch  = (((qr0 + 31) >> 6) >> 3) + 1;
    const int slot0 = b * SLOTS_PER_B + chunk_prefix(qt32);
    const _Float16* pp = Ppart + (size_t)slot0 * 4096;
    const float* lp = Lpart + (size_t)slot0 * 32;
    const int tid = threadIdx.x;

#pragma unroll
    for (int j = 0; j < 2; ++j) {
        int idx = tid + j * 256;            // half8 group 0..511
        int row = idx >> 4;
        float acc[8] = {0.f, 0.f, 0.f, 0.f, 0.f, 0.f, 0.f, 0.f};
        float l = 0.f;
        for (int c = 0; c < nch; ++c) {
            half8 v = *(const half8*)(pp + (size_t)c * 4096 + (size_t)idx * 8);
#pragma unroll
            for (int k = 0; k < 8; ++k) acc[k] += (float)v[k];
            l += lp[c * 32 + row];
        }
        float inv = 1.0f / l;
        float* ob = out + ((size_t)(b * S_) + qr0) * 128 + (size_t)idx * 8;
        floatx4 o0 = (floatx4){acc[0] * inv, acc[1] * inv, acc[2] * inv, acc[3] * inv};
        floatx4 o1 = (floatx4){acc[4] * inv, acc[5] * inv, acc[6] * inv, acc[7] * inv};
        *(floatx4*)ob = o0;
        *(floatx4*)(ob + 4) = o1;
    }
}

// ---------------- fallback (ws too small): R5 atomic path ----------------
__global__ __launch_bounds__(64) void attn_atomic_kernel(const _Float16* __restrict__ Qh,
                                                         const _Float16* __restrict__ Kp,
                                                         const _Float16* __restrict__ Vp,
                                                         float* __restrict__ out,
                                                         float* __restrict__ Lg) {
    __shared__ __align__(16) _Float16 Pl[2][16 * PLD];
    const int lane = threadIdx.x, quad = lane >> 4, l16 = lane & 15;
    const int b = blockIdx.x & 7, chunk = blockIdx.x >> 3;
    const int qt = 255 - blockIdx.y, qr0 = qt * 16;
    const int kt_max = qt >> 2, c0 = chunk * 8;
    if (c0 > kt_max) return;
    const int kend = min(kt_max, c0 + 7);
    const _Float16* Qb = Qh + ((size_t)(b * S_) + qr0 + l16) * 128;
    half8 aq[4];
#pragma unroll
    for (int c = 0; c < 4; ++c) aq[c] = *(const half8*)(Qb + c * 32 + quad * 8);
    floatx4 o[8];
#pragma unroll
    for (int i = 0; i < 8; ++i) o[i] = (floatx4){0.f, 0.f, 0.f, 0.f};
    float rsum[4] = {0.f, 0.f, 0.f, 0.f};
    const _Float16* Kb = Kp + (size_t)b * 524288;
    const _Float16* Vb = Vp + (size_t)b * 524288;
    for (int kt = c0; kt <= kend; ++kt) {
        half8 vf[2][8];
#pragma unroll
        for (int c2 = 0; c2 < 2; ++c2)
#pragma unroll
            for (int nt = 0; nt < 8; ++nt)
                vf[c2][nt] = *(const half8*)(Vb + (((size_t)(kt * 2 + c2) * 8 + nt) * 64 + lane) * 8);
        floatx4 s4[4];
#pragma unroll
        for (int t = 0; t < 4; ++t) {
            const _Float16* kp = Kb + ((size_t)((kt * 4 + t) * 4) * 64 + lane) * 8;
            floatx4 acc = (floatx4){0.f, 0.f, 0.f, 0.f};
#pragma unroll
            for (int c = 0; c < 4; ++c) {
                half8 bk = *(const half8*)(kp + c * 512);
                acc = __builtin_amdgcn_mfma_f32_16x16x32_f16(aq[c], bk, acc, 0, 0, 0);
            }
            s4[t] = acc;
        }
        if (kt == kt_max) {
#pragma unroll
            for (int t = 0; t < 4; ++t)
#pragma unroll
                for (int r = 0; r < 4; ++r) {
                    int kcol = kt * 64 + t * 16 + l16;
                    int qr = qr0 + quad * 4 + r;
                    if (kcol > qr) s4[t][r] += MASK_L2E;
                }
        }
        const int buf = kt & 1;
#pragma unroll
        for (int t = 0; t < 4; ++t)
#pragma unroll
            for (int r = 0; r < 4; ++r) {
                float p = __builtin_amdgcn_exp2f(s4[t][r]);
                rsum[r] += p;
                Pl[buf][(quad * 4 + r) * PLD + t * 16 + l16] = (_Float16)p;
            }
#pragma unroll
        for (int c2 = 0; c2 < 2; ++c2) {
            half8 ap = *(const half8*)&Pl[buf][l16 * PLD + c2 * 32 + quad * 8];
#pragma unroll
            for (int nt = 0; nt < 8; ++nt)
                o[nt] = __builtin_amdgcn_mfma_f32_16x16x32_f16(ap, vf[c2][nt], o[nt], 0, 0, 0);
        }
    }
#pragma unroll
    for (int off = 1; off <= 8; off <<= 1)
#pragma unroll
        for (int r = 0; r < 4; ++r)
            rsum[r] += __shfl_xor(rsum[r], off, 64);
    if (l16 == 0) {
#pragma unroll
        for (int r = 0; r < 4; ++r)
            atomicAdd(&Lg[(size_t)(b * S_) + qr0 + quad * 4 + r], rsum[r]);
    }
    float* ob = out + ((size_t)(b * S_) + qr0) * 128;
#pragma unroll
    for (int nt = 0; nt < 8; ++nt)
#pragma unroll
        for (int r = 0; r < 4; ++r)
            atomicAdd(&ob[(quad * 4 + r) * 128 + nt * 16 + l16], o[nt][r]);
}

__global__ __launch_bounds__(256) void norm_kernel(float* __restrict__ out,
                                                   const float* __restrict__ Lg) {
    int i = blockIdx.x * 256 + threadIdx.x;
    int row = i >> 5;
    floatx4 v = *(floatx4*)(out + (size_t)i * 4);
    float inv = 1.0f / Lg[row];
    v[0] *= inv; v[1] *= inv; v[2] *= inv; v[3] *= inv;
    *(floatx4*)(out + (size_t)i * 4) = v;
}

extern "C" void kernel_launch(void* const* d_in, const int* in_sizes, int n_in,
                              void* d_out, int out_size, void* d_ws, size_t ws_size,
                              hipStream_t stream) {
    const float* qkv = (const float*)d_in[0];
    float* out = (float*)d_out;
    const size_t MB = 1024 * 1024;
    _Float16* Qh = (_Float16*)d_ws;                          // 8 MB
    _Float16* Kp = (_Float16*)((char*)d_ws + 8 * MB);        // 8 MB
    _Float16* Vp = (_Float16*)((char*)d_ws + 16 * MB);       // 8 MB

    const size_t ppart_bytes = (size_t)B_ * SLOTS_PER_B * 4096 * sizeof(_Float16); // 36 MB
    const size_t need = 25 * MB + ppart_bytes;

    prep_kernel<<<dim3(128, B_), dim3(512), 0, stream>>>(qkv, Qh, Kp, Vp);

    if (ws_size >= need) {
        float*    Lpart = (float*)((char*)d_ws + 24 * MB);       // 576 KB
        _Float16* Ppart = (_Float16*)((char*)d_ws + 25 * MB);    // 36 MB
        attn_part_kernel<<<dim3(16, 128), dim3(256), 0, stream>>>(Qh, Kp, Vp, Ppart, Lpart);
        reduce_kernel<<<dim3(1024), dim3(256), 0, stream>>>(Ppart, Lpart, out);
    } else {
        float* Lg = (float*)((char*)d_ws + 24 * MB);             // 128 KB
        hipMemsetAsync(out, 0, (size_t)B_ * S_ * 128 * sizeof(float), stream);
        hipMemsetAsync(Lg, 0, (size_t)B_ * S_ * sizeof(float), stream);
        attn_atomic_kernel<<<dim3(64, 256), dim3(64), 0, stream>>>(Qh, Kp, Vp, out, Lg);
        norm_kernel<<<dim3(4096), dim3(256), 0, stream>>>(out, Lg);
    }
}

// Round 8
// 184.968 us; speedup vs baseline: 1.0492x; 1.0492x over previous
//
#include <hip/hip_runtime.h>
#include <math.h>

typedef _Float16 half8 __attribute__((ext_vector_type(8)));
typedef float floatx4 __attribute__((ext_vector_type(4)));
typedef float floatx2 __attribute__((ext_vector_type(2)));

#define B_ 8
#define S_ 4096
// scale = 1/sqrt(128) * log2(e): folded into Q so softmax exp is one v_exp_f32
#define SCALE_L2E 0.12751743008389106f
#define MASK_L2E  -14426.950408889634f   // -10000*log2(e): exp2 -> exact 0
#define L2_10K_OVER_128 0.10381025296522975f  // log2(10000)/128

#define PLD 72    // P LDS row stride (halfs) = 144B, 16B-aligned
#define KW  136   // prep K LDS row stride (halfs)
#define VW  24    // prep V^T LDS row stride (halfs)
#define OSTLD 136 // O-staging LDS row stride (halfs); 16xOSTLD fits in P region
#define SLOTS_PER_B 576   // sum over qt32 of ((qt32>>4)+1)

// slots before q-block qt32 (chunks(qt32) = (qt32>>4)+1)
__device__ __forceinline__ int chunk_prefix(int qt32) {
    int g = qt32 >> 4;
    return qt32 + 8 * g * (g - 1) + (qt32 - (g << 4)) * g;
}

// ---------------- kernel 1: prep (R6 exact) ----------------
// grid (256, 8), block 256: 16 seq rows per block.
//  Qh: RoPE(Q)*SCALE_L2E fp16 row-major [b][s][d]
//  Kp: frag-major: chunk(b,s16,c)[lane=quad*16+n][j] = K[s16*16+n][c*32+quad*8+j]
//  Vp: frag-major: chunk(b,kt,c2,nt)[lane=quad*16+n][j] = V[kt*64+c2*32+quad*8+j][nt*16+n]
__global__ __launch_bounds__(256) void prep_kernel(const float* __restrict__ qkv,
                                                   _Float16* __restrict__ Qh,
                                                   _Float16* __restrict__ Kp,
                                                   _Float16* __restrict__ Vp) {
    __shared__ __align__(16) _Float16 Kl[16][KW];
    __shared__ __align__(16) _Float16 Vt[128][VW];
    const int tid = threadIdx.x;
    const int b   = blockIdx.y;
    const int s0  = blockIdx.x * 16;

#pragma unroll
    for (int it = 0; it < 4; ++it) {
        int idx = tid + it * 256;
        int i = idx & 63, sr = idx >> 6, s = s0 + sr;
        const float* base = qkv + ((size_t)(b * S_ + s)) * 384 + 2 * i;
        floatx2 q2 = *(const floatx2*)base;
        floatx2 k2 = *(const floatx2*)(base + 128);
        float inv = exp2f(-(float)(2 * i) * L2_10K_OVER_128);
        float ang = (float)s * inv;
        float sn, cs;
        __sincosf(ang, &sn, &cs);
        size_t oq = ((size_t)(b * S_ + s)) * 128 + 2 * i;
        Qh[oq]     = (_Float16)((q2[0] * cs - q2[1] * sn) * SCALE_L2E);
        Qh[oq + 1] = (_Float16)((q2[0] * sn + q2[1] * cs) * SCALE_L2E);
        Kl[sr][2 * i]     = (_Float16)(k2[0] * cs - k2[1] * sn);
        Kl[sr][2 * i + 1] = (_Float16)(k2[0] * sn + k2[1] * cs);
    }
#pragma unroll
    for (int it = 0; it < 2; ++it) {
        int idx = tid + it * 256;
        int c = idx & 31, sr = idx >> 5;
        floatx4 v = *(const floatx4*)(qkv + ((size_t)(b * S_ + s0 + sr)) * 384 + 256 + c * 4);
#pragma unroll
        for (int j = 0; j < 4; ++j) Vt[c * 4 + j][sr] = (_Float16)v[j];
    }
    __syncthreads();

    {   // K frag-major out
        int c = tid >> 6, lane = tid & 63;
        int quad = lane >> 4, n = lane & 15;
        half8 val = *(const half8*)&Kl[n][c * 32 + quad * 8];
        int s16 = s0 >> 4;
        *(half8*)(Kp + (((size_t)(b * 256 + s16) * 4 + c) * 64 + lane) * 8) = val;
    }
    {   // V frag-major out
        int kt = s0 >> 6, c2 = (s0 >> 5) & 1, qp = (s0 >> 4) & 1;
        int nt = tid >> 5, lq = (tid >> 4) & 1, n = tid & 15;
        int quad = qp * 2 + lq;
        int lane = quad * 16 + n;
        half8 val = *(const half8*)&Vt[nt * 16 + n][lq * 8];
        *(half8*)(Vp + ((((size_t)(b * 64 + kt) * 2 + c2) * 8 + nt) * 64 + lane) * 8) = val;
    }
}

// ---------------- kernel 2a: split-K flash, L1-SHARED K/V ----------------
// grid (64, 32), block 256 (4 waves, NO barriers). Block = (b = bx&7,
// chunk = bx>>3, Q = 31-by). Wave wid owns qt32 = 4Q+wid (32 rows).
// All 4 waves walk the SAME kt range with IDENTICAL K/V frag addresses ->
// trailing waves hit L1 (32KB = one K-tile + one V-tile). Tiles beyond a
// wave's causal limit are fully masked (exp2 -> exact 0), so the slot and
// reduce structure is identical to R6.
__global__ __launch_bounds__(256) void attn_part_kernel(const _Float16* __restrict__ Qh,
                                                        const _Float16* __restrict__ Kp,
                                                        const _Float16* __restrict__ Vp,
                                                        _Float16* __restrict__ Ppart,
                                                        float* __restrict__ Lpart) {
    // per-wave LDS: 2 M-tiles x 2 buffers (kt parity) of 16xPLD
    __shared__ __align__(16) _Float16 SH[4][4 * 16 * PLD];

    const int tid   = threadIdx.x;
    const int wid   = tid >> 6;
    const int lane  = tid & 63;
    const int quad  = lane >> 4;
    const int l16   = lane & 15;
    const int b     = blockIdx.x & 7;
    const int chunk = blockIdx.x >> 3;
    const int Q     = 31 - blockIdx.y;      // big q-groups first
    const int nch   = (Q >> 2) + 1;
    if (chunk >= nch) return;               // block-uniform exit
    const int qt32  = Q * 4 + wid;
    const int qr0   = qt32 * 32;
    const int my_ktmax  = qt32 >> 1;        // this wave's causal limit
    const int blk_ktmax = 2 * Q + 1;        // block's kt range (largest wave)
    const int c0    = chunk * 8;
    const int kend  = min(blk_ktmax, c0 + 7);
    const int slot  = b * SLOTS_PER_B + chunk_prefix(qt32) + chunk;
    _Float16* sh = SH[wid];

    half8 aq[2][4];
#pragma unroll
    for (int tile = 0; tile < 2; ++tile) {
        const _Float16* Qb = Qh + ((size_t)(b * S_) + qr0 + tile * 16 + l16) * 128;
#pragma unroll
        for (int c = 0; c < 4; ++c) aq[tile][c] = *(const half8*)(Qb + c * 32 + quad * 8);
    }

    floatx4 o[2][8];
#pragma unroll
    for (int tile = 0; tile < 2; ++tile)
#pragma unroll
        for (int i = 0; i < 8; ++i) o[tile][i] = (floatx4){0.f, 0.f, 0.f, 0.f};
    float rsum[2][4] = {{0.f, 0.f, 0.f, 0.f}, {0.f, 0.f, 0.f, 0.f}};

    const _Float16* Kb = Kp + (size_t)b * 524288;
    const _Float16* Vb = Vp + (size_t)b * 524288;

    for (int kt = c0; kt <= kend; ++kt) {
        // V frags preload (identical addresses across the 4 waves -> L1)
        half8 vf[2][8];
#pragma unroll
        for (int c2 = 0; c2 < 2; ++c2)
#pragma unroll
            for (int nt = 0; nt < 8; ++nt)
                vf[c2][nt] = *(const half8*)(Vb + (((size_t)(kt * 2 + c2) * 8 + nt) * 64 + lane) * 8);

        // S = Q K^T : K frags loaded once, shared by both M-tiles
        floatx4 s4[2][4];
#pragma unroll
        for (int t = 0; t < 4; ++t) {
            const _Float16* kp = Kb + (((size_t)(kt * 16 + t * 4)) * 64 + lane) * 8;
            half8 bk[4];
#pragma unroll
            for (int c = 0; c < 4; ++c) bk[c] = *(const half8*)(kp + c * 512);
            floatx4 a0 = (floatx4){0.f, 0.f, 0.f, 0.f};
            floatx4 a1 = (floatx4){0.f, 0.f, 0.f, 0.f};
#pragma unroll
            for (int c = 0; c < 4; ++c) {
                a0 = __builtin_amdgcn_mfma_f32_16x16x32_f16(aq[0][c], bk[c], a0, 0, 0, 0);
                a1 = __builtin_amdgcn_mfma_f32_16x16x32_f16(aq[1][c], bk[c], a1, 0, 0, 0);
            }
            s4[0][t] = a0; s4[1][t] = a1;
        }

        // causal mask: any tile at/past this wave's diagonal (wave-uniform branch)
        if (kt >= my_ktmax) {
#pragma unroll
            for (int tile = 0; tile < 2; ++tile)
#pragma unroll
                for (int t = 0; t < 4; ++t)
#pragma unroll
                    for (int r = 0; r < 4; ++r) {
                        int kcol = kt * 64 + t * 16 + l16;
                        int qr   = qr0 + tile * 16 + quad * 4 + r;
                        if (kcol > qr) s4[tile][t][r] += MASK_L2E;
                    }
        }

        // p = exp2(s), lane-local l, P -> per-wave LDS (C->A transform, dbuf)
        const int buf = kt & 1;
#pragma unroll
        for (int tile = 0; tile < 2; ++tile)
#pragma unroll
            for (int t = 0; t < 4; ++t)
#pragma unroll
                for (int r = 0; r < 4; ++r) {
                    float p = __builtin_amdgcn_exp2f(s4[tile][t][r]);
                    rsum[tile][r] += p;
                    sh[(tile * 2 + buf) * (16 * PLD) + (quad * 4 + r) * PLD + t * 16 + l16] = (_Float16)p;
                }

        // O += P V
#pragma unroll
        for (int c2 = 0; c2 < 2; ++c2) {
#pragma unroll
            for (int tile = 0; tile < 2; ++tile) {
                half8 ap = *(const half8*)&sh[(tile * 2 + buf) * (16 * PLD) + l16 * PLD + c2 * 32 + quad * 8];
#pragma unroll
                for (int nt = 0; nt < 8; ++nt)
                    o[tile][nt] = __builtin_amdgcn_mfma_f32_16x16x32_f16(ap, vf[c2][nt], o[tile][nt], 0, 0, 0);
            }
        }
    }

    // l partials: reduce over l16, plain store
#pragma unroll
    for (int off = 1; off <= 8; off <<= 1)
#pragma unroll
        for (int tile = 0; tile < 2; ++tile)
#pragma unroll
            for (int r = 0; r < 4; ++r)
                rsum[tile][r] += __shfl_xor(rsum[tile][r], off, 64);
    if (l16 == 0) {
#pragma unroll
        for (int tile = 0; tile < 2; ++tile)
#pragma unroll
            for (int r = 0; r < 4; ++r)
                Lpart[(size_t)slot * 32 + tile * 16 + quad * 4 + r] = rsum[tile][r];
    }

    // O partial: per tile, C-layout -> LDS fp16 staging -> coalesced 16B stores
    _Float16* Ost = sh;   // 16 x OSTLD = 2176 halfs, fits in the 4608-half region
    _Float16* pp = Ppart + (size_t)slot * 4096;
#pragma unroll
    for (int tile = 0; tile < 2; ++tile) {
#pragma unroll
        for (int nt = 0; nt < 8; ++nt)
#pragma unroll
            for (int r = 0; r < 4; ++r)
                Ost[(quad * 4 + r) * OSTLD + nt * 16 + l16] = (_Float16)o[tile][nt][r];
#pragma unroll
        for (int i = 0; i < 4; ++i) {
            int idx = lane + i * 64;        // 16 rows x 16 half8-groups
            half8 v = *(const half8*)&Ost[(idx >> 4) * OSTLD + (idx & 15) * 8];
            *(half8*)(pp + (size_t)(tile * 2048 + idx * 8)) = v;
        }
    }
}

// ---------------- kernel 2b: reduce partials + normalize (R6 exact) ----------------
__global__ __launch_bounds__(256) void reduce_kernel(const _Float16* __restrict__ Ppart,
                                                     const float* __restrict__ Lpart,
                                                     float* __restrict__ out) {
    const int bid  = blockIdx.x;
    const int b    = bid >> 7;
    const int qt32 = bid & 127;
    const int qr0  = qt32 * 32;
    const int nch  = (qt32 >> 4) + 1;
    const int slot0 = b * SLOTS_PER_B + chunk_prefix(qt32);
    const _Float16* pp = Ppart + (size_t)slot0 * 4096;
    const float* lp = Lpart + (size_t)slot0 * 32;
    const int tid = threadIdx.x;

#pragma unroll
    for (int j = 0; j < 2; ++j) {
        int idx = tid + j * 256;            // half8 group 0..511
        int row = idx >> 4;
        float acc[8] = {0.f, 0.f, 0.f, 0.f, 0.f, 0.f, 0.f, 0.f};
        float l = 0.f;
        for (int c = 0; c < nch; ++c) {
            half8 v = *(const half8*)(pp + (size_t)c * 4096 + (size_t)idx * 8);
#pragma unroll
            for (int k = 0; k < 8; ++k) acc[k] += (float)v[k];
            l += lp[c * 32 + row];
        }
        float inv = 1.0f / l;
        float* ob = out + ((size_t)(b * S_) + qr0) * 128 + (size_t)idx * 8;
        floatx4 o0 = (floatx4){acc[0] * inv, acc[1] * inv, acc[2] * inv, acc[3] * inv};
        floatx4 o1 = (floatx4){acc[4] * inv, acc[5] * inv, acc[6] * inv, acc[7] * inv};
        *(floatx4*)ob = o0;
        *(floatx4*)(ob + 4) = o1;
    }
}

// ---------------- fallback (ws too small): R5 atomic path ----------------
__global__ __launch_bounds__(64) void attn_atomic_kernel(const _Float16* __restrict__ Qh,
                                                         const _Float16* __restrict__ Kp,
                                                         const _Float16* __restrict__ Vp,
                                                         float* __restrict__ out,
                                                         float* __restrict__ Lg) {
    __shared__ __align__(16) _Float16 Pl[2][16 * PLD];
    const int lane = threadIdx.x, quad = lane >> 4, l16 = lane & 15;
    const int b = blockIdx.x & 7, chunk = blockIdx.x >> 3;
    const int qt = 255 - blockIdx.y, qr0 = qt * 16;
    const int kt_max = qt >> 2, c0 = chunk * 8;
    if (c0 > kt_max) return;
    const int kend = min(kt_max, c0 + 7);
    const _Float16* Qb = Qh + ((size_t)(b * S_) + qr0 + l16) * 128;
    half8 aq[4];
#pragma unroll
    for (int c = 0; c < 4; ++c) aq[c] = *(const half8*)(Qb + c * 32 + quad * 8);
    floatx4 o[8];
#pragma unroll
    for (int i = 0; i < 8; ++i) o[i] = (floatx4){0.f, 0.f, 0.f, 0.f};
    float rsum[4] = {0.f, 0.f, 0.f, 0.f};
    const _Float16* Kb = Kp + (size_t)b * 524288;
    const _Float16* Vb = Vp + (size_t)b * 524288;
    for (int kt = c0; kt <= kend; ++kt) {
        half8 vf[2][8];
#pragma unroll
        for (int c2 = 0; c2 < 2; ++c2)
#pragma unroll
            for (int nt = 0; nt < 8; ++nt)
                vf[c2][nt] = *(const half8*)(Vb + (((size_t)(kt * 2 + c2) * 8 + nt) * 64 + lane) * 8);
        floatx4 s4[4];
#pragma unroll
        for (int t = 0; t < 4; ++t) {
            const _Float16* kp = Kb + ((size_t)((kt * 4 + t) * 4) * 64 + lane) * 8;
            floatx4 acc = (floatx4){0.f, 0.f, 0.f, 0.f};
#pragma unroll
            for (int c = 0; c < 4; ++c) {
                half8 bk = *(const half8*)(kp + c * 512);
                acc = __builtin_amdgcn_mfma_f32_16x16x32_f16(aq[c], bk, acc, 0, 0, 0);
            }
            s4[t] = acc;
        }
        if (kt == kt_max) {
#pragma unroll
            for (int t = 0; t < 4; ++t)
#pragma unroll
                for (int r = 0; r < 4; ++r) {
                    int kcol = kt * 64 + t * 16 + l16;
                    int qr = qr0 + quad * 4 + r;
                    if (kcol > qr) s4[t][r] += MASK_L2E;
                }
        }
        const int buf = kt & 1;
#pragma unroll
        for (int t = 0; t < 4; ++t)
#pragma unroll
            for (int r = 0; r < 4; ++r) {
                float p = __builtin_amdgcn_exp2f(s4[t][r]);
                rsum[r] += p;
                Pl[buf][(quad * 4 + r) * PLD + t * 16 + l16] = (_Float16)p;
            }
#pragma unroll
        for (int c2 = 0; c2 < 2; ++c2) {
            half8 ap = *(const half8*)&Pl[buf][l16 * PLD + c2 * 32 + quad * 8];
#pragma unroll
            for (int nt = 0; nt < 8; ++nt)
                o[nt] = __builtin_amdgcn_mfma_f32_16x16x32_f16(ap, vf[c2][nt], o[nt], 0, 0, 0);
        }
    }
#pragma unroll
    for (int off = 1; off <= 8; off <<= 1)
#pragma unroll
        for (int r = 0; r < 4; ++r)
            rsum[r] += __shfl_xor(rsum[r], off, 64);
    if (l16 == 0) {
#pragma unroll
        for (int r = 0; r < 4; ++r)
            atomicAdd(&Lg[(size_t)(b * S_) + qr0 + quad * 4 + r], rsum[r]);
    }
    float* ob = out + ((size_t)(b * S_) + qr0) * 128;
#pragma unroll
    for (int nt = 0; nt < 8; ++nt)
#pragma unroll
        for (int r = 0; r < 4; ++r)
            atomicAdd(&ob[(quad * 4 + r) * 128 + nt * 16 + l16], o[nt][r]);
}

__global__ __launch_bounds__(256) void norm_kernel(float* __restrict__ out,
                                                   const float* __restrict__ Lg) {
    int i = blockIdx.x * 256 + threadIdx.x;
    int row = i >> 5;
    floatx4 v = *(floatx4*)(out + (size_t)i * 4);
    float inv = 1.0f / Lg[row];
    v[0] *= inv; v[1] *= inv; v[2] *= inv; v[3] *= inv;
    *(floatx4*)(out + (size_t)i * 4) = v;
}

extern "C" void kernel_launch(void* const* d_in, const int* in_sizes, int n_in,
                              void* d_out, int out_size, void* d_ws, size_t ws_size,
                              hipStream_t stream) {
    const float* qkv = (const float*)d_in[0];
    float* out = (float*)d_out;
    const size_t MB = 1024 * 1024;
    _Float16* Qh = (_Float16*)d_ws;                          // 8 MB
    _Float16* Kp = (_Float16*)((char*)d_ws + 8 * MB);        // 8 MB
    _Float16* Vp = (_Float16*)((char*)d_ws + 16 * MB);       // 8 MB

    const size_t ppart_bytes = (size_t)B_ * SLOTS_PER_B * 4096 * sizeof(_Float16); // 36 MB
    const size_t need = 25 * MB + ppart_bytes;

    prep_kernel<<<dim3(256, B_), dim3(256), 0, stream>>>(qkv, Qh, Kp, Vp);

    if (ws_size >= need) {
        float*    Lpart = (float*)((char*)d_ws + 24 * MB);       // 576 KB
        _Float16* Ppart = (_Float16*)((char*)d_ws + 25 * MB);    // 36 MB
        attn_part_kernel<<<dim3(64, 32), dim3(256), 0, stream>>>(Qh, Kp, Vp, Ppart, Lpart);
        reduce_kernel<<<dim3(1024), dim3(256), 0, stream>>>(Ppart, Lpart, out);
    } else {
        float* Lg = (float*)((char*)d_ws + 24 * MB);             // 128 KB
        hipMemsetAsync(out, 0, (size_t)B_ * S_ * 128 * sizeof(float), stream);
        hipMemsetAsync(Lg, 0, (size_t)B_ * S_ * sizeof(float), stream);
        attn_atomic_kernel<<<dim3(64, 256), dim3(64), 0, stream>>>(Qh, Kp, Vp, out, Lg);
        norm_kernel<<<dim3(4096), dim3(256), 0, stream>>>(out, Lg);
    }
}